// Round 1
// baseline (104.744 us; speedup 1.0000x reference)
//
#include <hip/hip_runtime.h>
#include <math.h>

#define DEV __device__ __forceinline__

struct F3 { float x, y, z; };

DEV F3 mkf3(float x, float y, float z){ F3 r; r.x=x; r.y=y; r.z=z; return r; }
DEV F3 f3add(F3 a, F3 b){ return mkf3(a.x+b.x, a.y+b.y, a.z+b.z); }
DEV F3 f3sub(F3 a, F3 b){ return mkf3(a.x-b.x, a.y-b.y, a.z-b.z); }
DEV F3 f3scale(F3 a, float s){ return mkf3(a.x*s, a.y*s, a.z*s); }
DEV float f3dot(F3 a, F3 b){ return a.x*b.x + a.y*b.y + a.z*b.z; }
DEV F3 f3cross(F3 a, F3 b){
  return mkf3(a.y*b.z - a.z*b.y, a.z*b.x - a.x*b.z, a.x*b.y - a.y*b.x);
}
// reference: v / sqrt(max(sum(v*v), 1e-6)); fallback branch is dead (sqrt(clip)>=1e-3>1e-6)
DEV F3 f3dir(F3 v){
  float ss = f3dot(v, v);
  float inv = 1.0f / sqrtf(fmaxf(ss, 1e-6f));
  return f3scale(v, inv);
}
DEV float fast_silu(float x){
  return x * __builtin_amdgcn_rcpf(1.0f + __expf(-x));
}
DEV float fast_sigmoid(float x){
  return __builtin_amdgcn_rcpf(1.0f + __expf(-x));
}

// ---------------------------------------------------------------------------
// Kernel A: per-node frames [N,3,3] (stored fr[n*9 + j*3 + i], col i = axis i)
// plus delta_local [N,3]
// ---------------------------------------------------------------------------
__global__ void frames_kernel(const float* __restrict__ xc,
                              const float* __restrict__ xt,
                              float* __restrict__ frames,
                              float* __restrict__ dl, int N)
{
  int n = blockIdx.x * blockDim.x + threadIdx.x;
  if (n >= N) return;
  int pn = (n > 0) ? n - 1 : 0;       // prev = d[max(n-1,0)]
  int qn = (n < N - 1) ? n : N - 2;   // nxt  = d[min(n,N-2)]
  F3 prev = mkf3(xc[(pn+1)*3+0]-xc[pn*3+0], xc[(pn+1)*3+1]-xc[pn*3+1], xc[(pn+1)*3+2]-xc[pn*3+2]);
  F3 nxt  = mkf3(xc[(qn+1)*3+0]-xc[qn*3+0], xc[(qn+1)*3+1]-xc[qn*3+1], xc[(qn+1)*3+2]-xc[qn*3+2]);

  F3 tangent = f3dir(f3add(prev, nxt));
  F3 curv    = f3dir(f3sub(nxt, prev));
  float ct   = f3dot(curv, tangent);
  F3 ay      = f3dir(f3sub(curv, f3scale(tangent, ct)));
  F3 az      = f3dir(f3cross(tangent, ay));
  ay         = f3dir(f3cross(az, tangent));

  float* fr = frames + n * 9;
  fr[0] = tangent.x; fr[1] = ay.x; fr[2] = az.x;
  fr[3] = tangent.y; fr[4] = ay.y; fr[5] = az.y;
  fr[6] = tangent.z; fr[7] = ay.z; fr[8] = az.z;

  F3 delta = mkf3(xt[n*3+0]-xc[n*3+0], xt[n*3+1]-xc[n*3+1], xt[n*3+2]-xc[n*3+2]);
  dl[n*3+0] = f3dot(tangent, delta);
  dl[n*3+1] = f3dot(ay, delta);
  dl[n*3+2] = f3dot(az, delta);
}

// ---------------------------------------------------------------------------
// Kernel B: nh1 = silu([h, delta_local, t_emb] @ W_np1 + b_np1)   (4 rows/blk)
// ---------------------------------------------------------------------------
__global__ __launch_bounds__(256) void node_mlp1(
    const float* __restrict__ h, const float* __restrict__ dl,
    const float* __restrict__ tau,
    const float* __restrict__ W1, const float* __restrict__ b1,
    float* __restrict__ nh1, int N)
{
  const int n0 = blockIdx.x * 4, tid = threadIdx.x;
  __shared__ float feat[4][262];
  #pragma unroll
  for (int r = 0; r < 4; ++r) feat[r][tid] = h[(n0 + r) * 256 + tid];
  if (tid < 12) { int r = tid / 3, i = tid % 3; feat[r][256 + i] = dl[(n0 + r) * 3 + i]; }
  if (tid < 4) {
    float t = tau[0];
    feat[tid][259] = t; feat[tid][260] = sinf(t); feat[tid][261] = cosf(t);
  }
  __syncthreads();
  float bb = b1[tid];
  float a0 = bb, a1 = bb, a2 = bb, a3 = bb;
  #pragma unroll 2
  for (int k = 0; k < 262; ++k) {
    float w = W1[k * 256 + tid];
    a0 = fmaf(feat[0][k], w, a0);
    a1 = fmaf(feat[1][k], w, a1);
    a2 = fmaf(feat[2][k], w, a2);
    a3 = fmaf(feat[3][k], w, a3);
  }
  nh1[(n0+0)*256+tid] = fast_silu(a0);
  nh1[(n0+1)*256+tid] = fast_silu(a1);
  nh1[(n0+2)*256+tid] = fast_silu(a2);
  nh1[(n0+3)*256+tid] = fast_silu(a3);
}

// ---------------------------------------------------------------------------
// Kernel C: nh = silu(nh1 @ W_np2 + b_np2); src/dst/ns heads   (4 rows/blk)
// ---------------------------------------------------------------------------
__global__ __launch_bounds__(256) void node_mlp2(
    const float* __restrict__ nh1,
    const float* __restrict__ W2, const float* __restrict__ b2,
    const float* __restrict__ w_src, const float* __restrict__ b_src,
    const float* __restrict__ w_dst, const float* __restrict__ b_dst,
    const float* __restrict__ w_ns, const float* __restrict__ b_ns,
    float* __restrict__ nh, float* __restrict__ srcv,
    float* __restrict__ dstv, float* __restrict__ nsv, int N)
{
  const int n0 = blockIdx.x * 4, tid = threadIdx.x;
  __shared__ float f[4][256];
  __shared__ float red[4][4][3];  // [wave][row][head]
  #pragma unroll
  for (int r = 0; r < 4; ++r) f[r][tid] = nh1[(n0 + r) * 256 + tid];
  __syncthreads();
  float bb = b2[tid];
  float a[4] = {bb, bb, bb, bb};
  #pragma unroll 2
  for (int k = 0; k < 256; ++k) {
    float w = W2[k * 256 + tid];
    #pragma unroll
    for (int r = 0; r < 4; ++r) a[r] = fmaf(f[r][k], w, a[r]);
  }
  const float wsv = w_src[tid], wdv = w_dst[tid], wnv = w_ns[tid];
  const int wave = tid >> 6, lane = tid & 63;
  #pragma unroll
  for (int r = 0; r < 4; ++r) {
    float v = fast_silu(a[r]);
    nh[(n0 + r) * 256 + tid] = v;
    float ps = v * wsv, pd = v * wdv, pn = v * wnv;
    for (int off = 32; off; off >>= 1) {
      ps += __shfl_down(ps, off);
      pd += __shfl_down(pd, off);
      pn += __shfl_down(pn, off);
    }
    if (lane == 0) { red[wave][r][0] = ps; red[wave][r][1] = pd; red[wave][r][2] = pn; }
  }
  __syncthreads();
  if (tid < 4) {
    int r = tid;
    float s0 = 0.f, s1 = 0.f, s2 = 0.f;
    #pragma unroll
    for (int w = 0; w < 4; ++w) { s0 += red[w][r][0]; s1 += red[w][r][1]; s2 += red[w][r][2]; }
    srcv[n0 + r] = s0 + b_src[0];
    dstv[n0 + r] = s1 + b_dst[0];
    nsv[n0 + r]  = fast_sigmoid(s2 + b_ns[0]);
  }
}

// ---------------------------------------------------------------------------
// Kernel D: fused edge MLP + row softmax + message aggregation.
// One block per row n; thread handles 4 m's (N==1024). No N^2 materialization.
// ---------------------------------------------------------------------------
__global__ __launch_bounds__(256) void edge_softmax(
    const float* __restrict__ x_t, const float* __restrict__ frames,
    const float* __restrict__ srcv, const float* __restrict__ dstv,
    const float* __restrict__ nsv,
    const float* __restrict__ W_eg1, const float* __restrict__ b_eg1,
    const float* __restrict__ w_eg2, const float* __restrict__ b_eg2,
    float* __restrict__ msgs, int N)
{
  const int n = blockIdx.x, tid = threadIdx.x;
  __shared__ float4 wA[128];   // {W_eg1[0][j], W_eg1[1][j], W_eg1[2][j], W_eg1[3][j]}
  __shared__ float2 wB[128];   // {b_eg1[j], w_eg2[j]}
  __shared__ float frs[9], xns[3], srcs;
  __shared__ float redmax[4];
  __shared__ float red[4][4];  // [wave][{sum,a0,a1,a2}]

  if (tid < 128) {
    wA[tid] = make_float4(W_eg1[tid], W_eg1[128 + tid], W_eg1[256 + tid], W_eg1[384 + tid]);
    wB[tid] = make_float2(b_eg1[tid], w_eg2[tid]);
  }
  if (tid < 9) frs[tid] = frames[n * 9 + tid];
  if (tid < 3) xns[tid] = x_t[n * 3 + tid];
  if (tid == 0) srcs = srcv[n];
  __syncthreads();

  const float f0 = frs[0], f1 = frs[1], f2 = frs[2],
              f3_ = frs[3], f4 = frs[4], f5 = frs[5],
              f6 = frs[6], f7 = frs[7], f8 = frs[8];
  const float x0 = xns[0], x1 = xns[1], x2 = xns[2];
  const float sn = srcs;
  const float b2 = b_eg2[0];

  float l[4], r0[4], r1[4], r2[4];
  float lmax = -3.4e38f;

  #pragma unroll
  for (int mi = 0; mi < 4; ++mi) {
    const int m = mi * 256 + tid;
    float rx = x_t[m * 3 + 0] - x0;
    float ry = x_t[m * 3 + 1] - x1;
    float rz = x_t[m * 3 + 2] - x2;
    float rl0 = f0 * rx + f3_ * ry + f6 * rz;
    float rl1 = f1 * rx + f4 * ry + f7 * rz;
    float rl2 = f2 * rx + f5 * ry + f8 * rz;
    float dist = sqrtf(rl0 * rl0 + rl1 * rl1 + rl2 * rl2);
    float acc = b2;
    #pragma unroll 16
    for (int j = 0; j < 128; ++j) {
      float4 w = wA[j];
      float2 v = wB[j];
      float t = fmaf(w.x, rl0, fmaf(w.y, rl1, fmaf(w.z, rl2, fmaf(w.w, dist, v.x))));
      float s = t * __builtin_amdgcn_rcpf(1.0f + __expf(-t));
      acc = fmaf(s, v.y, acc);
    }
    float lg = sn + dstv[m] + acc;
    if (m == n) lg = -10000.0f;
    l[mi] = lg; r0[mi] = rl0; r1[mi] = rl1; r2[mi] = rl2;
    lmax = fmaxf(lmax, lg);
  }

  // block max reduce
  for (int off = 32; off; off >>= 1) lmax = fmaxf(lmax, __shfl_down(lmax, off));
  const int wave = tid >> 6, lane = tid & 63;
  if (lane == 0) redmax[wave] = lmax;
  __syncthreads();
  const float mx = fmaxf(fmaxf(redmax[0], redmax[1]), fmaxf(redmax[2], redmax[3]));

  float sum = 0.f, a0 = 0.f, a1 = 0.f, a2 = 0.f;
  #pragma unroll
  for (int mi = 0; mi < 4; ++mi) {
    const int m = mi * 256 + tid;
    float e = __expf(l[mi] - mx);     // diag: exp(-10000-mx) underflows to 0
    sum += e;
    float w = e * nsv[m];
    a0 = fmaf(w, r0[mi], a0);
    a1 = fmaf(w, r1[mi], a1);
    a2 = fmaf(w, r2[mi], a2);
  }
  for (int off = 32; off; off >>= 1) {
    sum += __shfl_down(sum, off);
    a0 += __shfl_down(a0, off);
    a1 += __shfl_down(a1, off);
    a2 += __shfl_down(a2, off);
  }
  if (lane == 0) { red[wave][0] = sum; red[wave][1] = a0; red[wave][2] = a1; red[wave][3] = a2; }
  __syncthreads();
  if (tid == 0) {
    float Z  = red[0][0] + red[1][0] + red[2][0] + red[3][0];
    float m0 = red[0][1] + red[1][1] + red[2][1] + red[3][1];
    float m1 = red[0][2] + red[1][2] + red[2][2] + red[3][2];
    float m2 = red[0][3] + red[1][3] + red[2][3] + red[3][3];
    float invZ = 1.0f / Z;
    msgs[n * 3 + 0] = m0 * invZ;
    msgs[n * 3 + 1] = m1 * invZ;
    msgs[n * 3 + 2] = m2 * invZ;
  }
}

// ---------------------------------------------------------------------------
// Kernel E: out MLP: silu([nh, dl, msgs] @ W_out1 + b_out1) @ W_out2 + b_out2,
// then vel = . + 0.25*msgs, out = frames @ vel.   (4 rows/blk)
// ---------------------------------------------------------------------------
__global__ __launch_bounds__(256) void out_mlp(
    const float* __restrict__ nh, const float* __restrict__ dl,
    const float* __restrict__ msgs, const float* __restrict__ frames,
    const float* __restrict__ W1, const float* __restrict__ b1,
    const float* __restrict__ W2, const float* __restrict__ b2,
    float* __restrict__ out, int N)
{
  const int n0 = blockIdx.x * 4, tid = threadIdx.x;
  __shared__ float uf[4][262];
  __shared__ float red[4][4][3];  // [wave][row][i]
  #pragma unroll
  for (int r = 0; r < 4; ++r) uf[r][tid] = nh[(n0 + r) * 256 + tid];
  if (tid < 24) {
    int r = tid / 6, c = tid % 6;
    uf[r][256 + c] = (c < 3) ? dl[(n0 + r) * 3 + c] : msgs[(n0 + r) * 3 + (c - 3)];
  }
  __syncthreads();
  float bb = b1[tid];
  float a[4] = {bb, bb, bb, bb};
  #pragma unroll 2
  for (int k = 0; k < 262; ++k) {
    float w = W1[k * 256 + tid];
    #pragma unroll
    for (int r = 0; r < 4; ++r) a[r] = fmaf(uf[r][k], w, a[r]);
  }
  const float w0 = W2[tid * 3 + 0], w1 = W2[tid * 3 + 1], w2 = W2[tid * 3 + 2];
  const int wave = tid >> 6, lane = tid & 63;
  #pragma unroll
  for (int r = 0; r < 4; ++r) {
    float hid = fast_silu(a[r]);
    float p0 = hid * w0, p1 = hid * w1, p2 = hid * w2;
    for (int off = 32; off; off >>= 1) {
      p0 += __shfl_down(p0, off);
      p1 += __shfl_down(p1, off);
      p2 += __shfl_down(p2, off);
    }
    if (lane == 0) { red[wave][r][0] = p0; red[wave][r][1] = p1; red[wave][r][2] = p2; }
  }
  __syncthreads();
  if (tid < 4) {
    int r = tid, n = n0 + r;
    float s0 = 0.f, s1 = 0.f, s2 = 0.f;
    #pragma unroll
    for (int w = 0; w < 4; ++w) { s0 += red[w][r][0]; s1 += red[w][r][1]; s2 += red[w][r][2]; }
    float m0 = msgs[n * 3 + 0], m1 = msgs[n * 3 + 1], m2 = msgs[n * 3 + 2];
    float v0 = s0 + b2[0] + 0.25f * m0;
    float v1 = s1 + b2[1] + 0.25f * m1;
    float v2 = s2 + b2[2] + 0.25f * m2;
    const float* fr = frames + n * 9;
    out[n * 3 + 0] = fr[0] * v0 + fr[1] * v1 + fr[2] * v2;
    out[n * 3 + 1] = fr[3] * v0 + fr[4] * v1 + fr[5] * v2;
    out[n * 3 + 2] = fr[6] * v0 + fr[7] * v1 + fr[8] * v2;
  }
}

// ---------------------------------------------------------------------------
extern "C" void kernel_launch(void* const* d_in, const int* in_sizes, int n_in,
                              void* d_out, int out_size, void* d_ws, size_t ws_size,
                              hipStream_t stream) {
  const float* h      = (const float*)d_in[0];
  const float* x_t    = (const float*)d_in[1];
  const float* x_cond = (const float*)d_in[2];
  const float* tau    = (const float*)d_in[3];
  const float* W_np1  = (const float*)d_in[4];
  const float* b_np1  = (const float*)d_in[5];
  const float* W_np2  = (const float*)d_in[6];
  const float* b_np2  = (const float*)d_in[7];
  const float* w_src  = (const float*)d_in[8];
  const float* b_src  = (const float*)d_in[9];
  const float* w_dst  = (const float*)d_in[10];
  const float* b_dst  = (const float*)d_in[11];
  const float* w_ns   = (const float*)d_in[12];
  const float* b_ns   = (const float*)d_in[13];
  const float* W_eg1  = (const float*)d_in[14];
  const float* b_eg1  = (const float*)d_in[15];
  const float* w_eg2  = (const float*)d_in[16];
  const float* b_eg2  = (const float*)d_in[17];
  const float* W_out1 = (const float*)d_in[18];
  const float* b_out1 = (const float*)d_in[19];
  const float* W_out2 = (const float*)d_in[20];
  const float* b_out2 = (const float*)d_in[21];
  float* out = (float*)d_out;

  const int N = in_sizes[1] / 3;  // 1024

  float* ws     = (float*)d_ws;
  float* frames = ws;                 // N*9
  float* dl     = frames + N * 9;     // N*3
  float* nh1    = dl + N * 3;         // N*256
  float* nh     = nh1 + N * 256;      // N*256
  float* srcv   = nh + N * 256;       // N
  float* dstv   = srcv + N;           // N
  float* nsv    = dstv + N;           // N
  float* msgs   = nsv + N;            // N*3

  frames_kernel<<<(N + 255) / 256, 256, 0, stream>>>(x_cond, x_t, frames, dl, N);
  node_mlp1<<<N / 4, 256, 0, stream>>>(h, dl, tau, W_np1, b_np1, nh1, N);
  node_mlp2<<<N / 4, 256, 0, stream>>>(nh1, W_np2, b_np2, w_src, b_src,
                                       w_dst, b_dst, w_ns, b_ns,
                                       nh, srcv, dstv, nsv, N);
  edge_softmax<<<N, 256, 0, stream>>>(x_t, frames, srcv, dstv, nsv,
                                      W_eg1, b_eg1, w_eg2, b_eg2, msgs, N);
  out_mlp<<<N / 4, 256, 0, stream>>>(nh, dl, msgs, frames,
                                     W_out1, b_out1, W_out2, b_out2, out, N);
}

// Round 2
// 75.376 us; speedup vs baseline: 1.3896x; 1.3896x over previous
//
#include <hip/hip_runtime.h>
#include <math.h>

#define DEV __device__ __forceinline__

struct F3 { float x, y, z; };

DEV F3 mkf3(float x, float y, float z){ F3 r; r.x=x; r.y=y; r.z=z; return r; }
DEV F3 f3add(F3 a, F3 b){ return mkf3(a.x+b.x, a.y+b.y, a.z+b.z); }
DEV F3 f3sub(F3 a, F3 b){ return mkf3(a.x-b.x, a.y-b.y, a.z-b.z); }
DEV F3 f3scale(F3 a, float s){ return mkf3(a.x*s, a.y*s, a.z*s); }
DEV float f3dot(F3 a, F3 b){ return a.x*b.x + a.y*b.y + a.z*b.z; }
DEV F3 f3cross(F3 a, F3 b){
  return mkf3(a.y*b.z - a.z*b.y, a.z*b.x - a.x*b.z, a.x*b.y - a.y*b.x);
}
// reference: v / sqrt(max(sum(v*v), 1e-6)); fallback branch is dead
DEV F3 f3dir(F3 v){
  float ss = f3dot(v, v);
  float inv = 1.0f / sqrtf(fmaxf(ss, 1e-6f));
  return f3scale(v, inv);
}
DEV float fast_silu(float x){
  return x * __builtin_amdgcn_rcpf(1.0f + __expf(-x));
}
DEV float fast_sigmoid(float x){
  return __builtin_amdgcn_rcpf(1.0f + __expf(-x));
}

// ---------------------------------------------------------------------------
// Kernel A: per-node frames [N,3,3] (fr[n*9 + i*3 + j] = axis_j component i is
// stored row-major as fr[i*3+j], col j = axis j) plus delta_local [N,3]
// ---------------------------------------------------------------------------
__global__ void frames_kernel(const float* __restrict__ xc,
                              const float* __restrict__ xt,
                              float* __restrict__ frames,
                              float* __restrict__ dl, int N)
{
  int n = blockIdx.x * blockDim.x + threadIdx.x;
  if (n >= N) return;
  int pn = (n > 0) ? n - 1 : 0;       // prev = d[max(n-1,0)]
  int qn = (n < N - 1) ? n : N - 2;   // nxt  = d[min(n,N-2)]
  F3 prev = mkf3(xc[(pn+1)*3+0]-xc[pn*3+0], xc[(pn+1)*3+1]-xc[pn*3+1], xc[(pn+1)*3+2]-xc[pn*3+2]);
  F3 nxt  = mkf3(xc[(qn+1)*3+0]-xc[qn*3+0], xc[(qn+1)*3+1]-xc[qn*3+1], xc[(qn+1)*3+2]-xc[qn*3+2]);

  F3 tangent = f3dir(f3add(prev, nxt));
  F3 curv    = f3dir(f3sub(nxt, prev));
  float ct   = f3dot(curv, tangent);
  F3 ay      = f3dir(f3sub(curv, f3scale(tangent, ct)));
  F3 az      = f3dir(f3cross(tangent, ay));
  ay         = f3dir(f3cross(az, tangent));

  float* fr = frames + n * 9;
  fr[0] = tangent.x; fr[1] = ay.x; fr[2] = az.x;
  fr[3] = tangent.y; fr[4] = ay.y; fr[5] = az.y;
  fr[6] = tangent.z; fr[7] = ay.z; fr[8] = az.z;

  F3 delta = mkf3(xt[n*3+0]-xc[n*3+0], xt[n*3+1]-xc[n*3+1], xt[n*3+2]-xc[n*3+2]);
  dl[n*3+0] = f3dot(tangent, delta);
  dl[n*3+1] = f3dot(ay, delta);
  dl[n*3+2] = f3dot(az, delta);
}

// ---------------------------------------------------------------------------
// Kernel B: nh1 = silu([h, delta_local, t_emb] @ W_np1 + b_np1)
// 4 rows/block; transposed float4 activation tile; 64-deep W prefetch.
// ---------------------------------------------------------------------------
__global__ __launch_bounds__(256) void node_mlp1(
    const float* __restrict__ h, const float* __restrict__ dl,
    const float* __restrict__ tau,
    const float* __restrict__ W1, const float* __restrict__ b1,
    float* __restrict__ nh1, int N)
{
  const int n0 = blockIdx.x * 4, tid = threadIdx.x;
  __shared__ float4 feat4[262];    // feat4[k] = {row0,row1,row2,row3}[k]
  {
    const float* hp = h + n0 * 256 + tid;
    feat4[tid] = make_float4(hp[0], hp[256], hp[512], hp[768]);
  }
  if (tid < 6) {
    int k = 256 + tid;
    float4 v;
    if (tid < 3) {
      v = make_float4(dl[(n0+0)*3+tid], dl[(n0+1)*3+tid],
                      dl[(n0+2)*3+tid], dl[(n0+3)*3+tid]);
    } else {
      float t = tau[0];
      float s = (tid == 3) ? t : ((tid == 4) ? sinf(t) : cosf(t));
      v = make_float4(s, s, s, s);
    }
    feat4[k] = v;
  }
  __syncthreads();

  float bb = b1[tid];
  float a0 = bb, a1 = bb, a2 = bb, a3 = bb;
  const float* Wp = W1 + tid;
  for (int kb = 0; kb < 256; kb += 64) {
    float w[64];
    #pragma unroll
    for (int u = 0; u < 64; ++u) w[u] = Wp[(kb + u) * 256];
    #pragma unroll
    for (int u = 0; u < 64; ++u) {
      float4 f = feat4[kb + u];
      a0 = fmaf(f.x, w[u], a0); a1 = fmaf(f.y, w[u], a1);
      a2 = fmaf(f.z, w[u], a2); a3 = fmaf(f.w, w[u], a3);
    }
  }
  #pragma unroll
  for (int k = 256; k < 262; ++k) {
    float w = Wp[k * 256];
    float4 f = feat4[k];
    a0 = fmaf(f.x, w, a0); a1 = fmaf(f.y, w, a1);
    a2 = fmaf(f.z, w, a2); a3 = fmaf(f.w, w, a3);
  }
  nh1[(n0+0)*256+tid] = fast_silu(a0);
  nh1[(n0+1)*256+tid] = fast_silu(a1);
  nh1[(n0+2)*256+tid] = fast_silu(a2);
  nh1[(n0+3)*256+tid] = fast_silu(a3);
}

// ---------------------------------------------------------------------------
// Kernel C: nh = silu(nh1 @ W_np2 + b_np2); src/dst/ns heads
// ---------------------------------------------------------------------------
__global__ __launch_bounds__(256) void node_mlp2(
    const float* __restrict__ nh1,
    const float* __restrict__ W2, const float* __restrict__ b2,
    const float* __restrict__ w_src, const float* __restrict__ b_src,
    const float* __restrict__ w_dst, const float* __restrict__ b_dst,
    const float* __restrict__ w_ns, const float* __restrict__ b_ns,
    float* __restrict__ nh, float* __restrict__ srcv,
    float* __restrict__ dstv, float* __restrict__ nsv, int N)
{
  const int n0 = blockIdx.x * 4, tid = threadIdx.x;
  __shared__ float4 feat4[256];
  __shared__ float red[4][4][3];  // [wave][row][head]
  {
    const float* hp = nh1 + n0 * 256 + tid;
    feat4[tid] = make_float4(hp[0], hp[256], hp[512], hp[768]);
  }
  __syncthreads();

  float bb = b2[tid];
  float a0 = bb, a1 = bb, a2 = bb, a3 = bb;
  const float* Wp = W2 + tid;
  for (int kb = 0; kb < 256; kb += 64) {
    float w[64];
    #pragma unroll
    for (int u = 0; u < 64; ++u) w[u] = Wp[(kb + u) * 256];
    #pragma unroll
    for (int u = 0; u < 64; ++u) {
      float4 f = feat4[kb + u];
      a0 = fmaf(f.x, w[u], a0); a1 = fmaf(f.y, w[u], a1);
      a2 = fmaf(f.z, w[u], a2); a3 = fmaf(f.w, w[u], a3);
    }
  }

  const float wsv = w_src[tid], wdv = w_dst[tid], wnv = w_ns[tid];
  const int wave = tid >> 6, lane = tid & 63;
  float va[4] = {fast_silu(a0), fast_silu(a1), fast_silu(a2), fast_silu(a3)};
  #pragma unroll
  for (int r = 0; r < 4; ++r) {
    nh[(n0 + r) * 256 + tid] = va[r];
    float ps = va[r] * wsv, pd = va[r] * wdv, pn = va[r] * wnv;
    for (int off = 32; off; off >>= 1) {
      ps += __shfl_down(ps, off);
      pd += __shfl_down(pd, off);
      pn += __shfl_down(pn, off);
    }
    if (lane == 0) { red[wave][r][0] = ps; red[wave][r][1] = pd; red[wave][r][2] = pn; }
  }
  __syncthreads();
  if (tid < 4) {
    int r = tid;
    float s0 = 0.f, s1 = 0.f, s2 = 0.f;
    #pragma unroll
    for (int w = 0; w < 4; ++w) { s0 += red[w][r][0]; s1 += red[w][r][1]; s2 += red[w][r][2]; }
    srcv[n0 + r] = s0 + b_src[0];
    dstv[n0 + r] = s1 + b_dst[0];
    nsv[n0 + r]  = fast_sigmoid(s2 + b_ns[0]);
  }
}

// ---------------------------------------------------------------------------
// Kernel D: fused edge MLP + row softmax + message aggregation.
// One block (512 thr, 8 waves) per row n; thread handles 2 m's.
// Layer-1 weights pre-scaled by -log2e so SiLU = exp2 + rcp only.
// ---------------------------------------------------------------------------
__global__ __launch_bounds__(512, 8) void edge_softmax(
    const float* __restrict__ x_t, const float* __restrict__ frames,
    const float* __restrict__ srcv, const float* __restrict__ dstv,
    const float* __restrict__ nsv,
    const float* __restrict__ W_eg1, const float* __restrict__ b_eg1,
    const float* __restrict__ w_eg2, const float* __restrict__ b_eg2,
    float* __restrict__ msgs, int N)
{
  const int n = blockIdx.x, tid = threadIdx.x;
  __shared__ float4 wA[128];   // -log2e * {W_eg1[0][j],W_eg1[1][j],W_eg1[2][j],W_eg1[3][j]}
  __shared__ float2 wB[128];   // {-log2e*b_eg1[j], -ln2*w_eg2[j]}
  __shared__ float frs[9], xns[3], srcs_;
  __shared__ float redmax[8];
  __shared__ float red[8][4];  // [wave][{sum,a0,a1,a2}]

  if (tid < 128) {
    const float nl2e = -1.44269504088896340736f;  // -log2(e)
    const float nln2 = -0.69314718055994530942f;  // -ln(2)
    wA[tid] = make_float4(nl2e * W_eg1[tid], nl2e * W_eg1[128 + tid],
                          nl2e * W_eg1[256 + tid], nl2e * W_eg1[384 + tid]);
    wB[tid] = make_float2(nl2e * b_eg1[tid], nln2 * w_eg2[tid]);
  }
  if (tid < 9) frs[tid] = frames[n * 9 + tid];
  if (tid < 3) xns[tid] = x_t[n * 3 + tid];
  if (tid == 0) srcs_ = srcv[n];
  __syncthreads();

  const float f0 = frs[0], f1 = frs[1], f2 = frs[2],
              f3_ = frs[3], f4 = frs[4], f5 = frs[5],
              f6 = frs[6], f7 = frs[7], f8 = frs[8];
  const float x0 = xns[0], x1 = xns[1], x2 = xns[2];
  const float sn = srcs_;
  const float b2v = b_eg2[0];

  float l[2], r0[2], r1[2], r2[2];
  float lmax = -3.4e38f;

  #pragma unroll
  for (int mi = 0; mi < 2; ++mi) {
    const int m = mi * 512 + tid;
    float rx = x_t[m * 3 + 0] - x0;
    float ry = x_t[m * 3 + 1] - x1;
    float rz = x_t[m * 3 + 2] - x2;
    float rl0 = f0 * rx + f3_ * ry + f6 * rz;
    float rl1 = f1 * rx + f4 * ry + f7 * rz;
    float rl2 = f2 * rx + f5 * ry + f8 * rz;
    float dist = sqrtf(rl0 * rl0 + rl1 * rl1 + rl2 * rl2);
    float acc = b2v;
    #pragma unroll 8
    for (int j = 0; j < 128; ++j) {
      float4 w = wA[j];
      float2 v = wB[j];
      // tp = -log2e * (W.r + b);  exp2(tp) = exp(-t)
      float tp = fmaf(w.x, rl0, fmaf(w.y, rl1, fmaf(w.z, rl2, fmaf(w.w, dist, v.x))));
      float e  = __builtin_amdgcn_exp2f(tp);
      float sg = __builtin_amdgcn_rcpf(1.0f + e);   // sigma(t)
      acc = fmaf(v.y, tp * sg, acc);                // w2 * t * sigma(t)
    }
    float lg = sn + dstv[m] + acc;
    if (m == n) lg = -10000.0f;
    l[mi] = lg; r0[mi] = rl0; r1[mi] = rl1; r2[mi] = rl2;
    lmax = fmaxf(lmax, lg);
  }

  // block max reduce (8 waves)
  for (int off = 32; off; off >>= 1) lmax = fmaxf(lmax, __shfl_down(lmax, off));
  const int wave = tid >> 6, lane = tid & 63;
  if (lane == 0) redmax[wave] = lmax;
  __syncthreads();
  float mx = redmax[0];
  #pragma unroll
  for (int w = 1; w < 8; ++w) mx = fmaxf(mx, redmax[w]);

  float sum = 0.f, a0 = 0.f, a1 = 0.f, a2 = 0.f;
  #pragma unroll
  for (int mi = 0; mi < 2; ++mi) {
    const int m = mi * 512 + tid;
    float e = __expf(l[mi] - mx);     // diag underflows to 0
    sum += e;
    float w = e * nsv[m];
    a0 = fmaf(w, r0[mi], a0);
    a1 = fmaf(w, r1[mi], a1);
    a2 = fmaf(w, r2[mi], a2);
  }
  for (int off = 32; off; off >>= 1) {
    sum += __shfl_down(sum, off);
    a0 += __shfl_down(a0, off);
    a1 += __shfl_down(a1, off);
    a2 += __shfl_down(a2, off);
  }
  if (lane == 0) { red[wave][0] = sum; red[wave][1] = a0; red[wave][2] = a1; red[wave][3] = a2; }
  __syncthreads();
  if (tid == 0) {
    float Z = 0.f, m0 = 0.f, m1 = 0.f, m2 = 0.f;
    #pragma unroll
    for (int w = 0; w < 8; ++w) {
      Z += red[w][0]; m0 += red[w][1]; m1 += red[w][2]; m2 += red[w][3];
    }
    float invZ = 1.0f / Z;
    msgs[n * 3 + 0] = m0 * invZ;
    msgs[n * 3 + 1] = m1 * invZ;
    msgs[n * 3 + 2] = m2 * invZ;
  }
}

// ---------------------------------------------------------------------------
// Kernel E: out MLP + 0.25*msgs + frame rotation
// ---------------------------------------------------------------------------
__global__ __launch_bounds__(256) void out_mlp(
    const float* __restrict__ nh, const float* __restrict__ dl,
    const float* __restrict__ msgs, const float* __restrict__ frames,
    const float* __restrict__ W1, const float* __restrict__ b1,
    const float* __restrict__ W2, const float* __restrict__ b2,
    float* __restrict__ out, int N)
{
  const int n0 = blockIdx.x * 4, tid = threadIdx.x;
  __shared__ float4 feat4[262];
  __shared__ float red[4][4][3];  // [wave][row][i]
  {
    const float* hp = nh + n0 * 256 + tid;
    feat4[tid] = make_float4(hp[0], hp[256], hp[512], hp[768]);
  }
  if (tid < 6) {
    int k = 256 + tid;
    float4 v;
    if (tid < 3) {
      v = make_float4(dl[(n0+0)*3+tid], dl[(n0+1)*3+tid],
                      dl[(n0+2)*3+tid], dl[(n0+3)*3+tid]);
    } else {
      int c = tid - 3;
      v = make_float4(msgs[(n0+0)*3+c], msgs[(n0+1)*3+c],
                      msgs[(n0+2)*3+c], msgs[(n0+3)*3+c]);
    }
    feat4[k] = v;
  }
  __syncthreads();

  float bb = b1[tid];
  float a0 = bb, a1 = bb, a2 = bb, a3 = bb;
  const float* Wp = W1 + tid;
  for (int kb = 0; kb < 256; kb += 64) {
    float w[64];
    #pragma unroll
    for (int u = 0; u < 64; ++u) w[u] = Wp[(kb + u) * 256];
    #pragma unroll
    for (int u = 0; u < 64; ++u) {
      float4 f = feat4[kb + u];
      a0 = fmaf(f.x, w[u], a0); a1 = fmaf(f.y, w[u], a1);
      a2 = fmaf(f.z, w[u], a2); a3 = fmaf(f.w, w[u], a3);
    }
  }
  #pragma unroll
  for (int k = 256; k < 262; ++k) {
    float w = Wp[k * 256];
    float4 f = feat4[k];
    a0 = fmaf(f.x, w, a0); a1 = fmaf(f.y, w, a1);
    a2 = fmaf(f.z, w, a2); a3 = fmaf(f.w, w, a3);
  }

  const float w0 = W2[tid * 3 + 0], w1 = W2[tid * 3 + 1], w2 = W2[tid * 3 + 2];
  const int wave = tid >> 6, lane = tid & 63;
  float va[4] = {fast_silu(a0), fast_silu(a1), fast_silu(a2), fast_silu(a3)};
  #pragma unroll
  for (int r = 0; r < 4; ++r) {
    float p0 = va[r] * w0, p1 = va[r] * w1, p2 = va[r] * w2;
    for (int off = 32; off; off >>= 1) {
      p0 += __shfl_down(p0, off);
      p1 += __shfl_down(p1, off);
      p2 += __shfl_down(p2, off);
    }
    if (lane == 0) { red[wave][r][0] = p0; red[wave][r][1] = p1; red[wave][r][2] = p2; }
  }
  __syncthreads();
  if (tid < 4) {
    int r = tid, n = n0 + r;
    float s0 = 0.f, s1 = 0.f, s2 = 0.f;
    #pragma unroll
    for (int w = 0; w < 4; ++w) { s0 += red[w][r][0]; s1 += red[w][r][1]; s2 += red[w][r][2]; }
    float m0 = msgs[n * 3 + 0], m1 = msgs[n * 3 + 1], m2 = msgs[n * 3 + 2];
    float v0 = s0 + b2[0] + 0.25f * m0;
    float v1 = s1 + b2[1] + 0.25f * m1;
    float v2 = s2 + b2[2] + 0.25f * m2;
    const float* fr = frames + n * 9;
    out[n * 3 + 0] = fr[0] * v0 + fr[1] * v1 + fr[2] * v2;
    out[n * 3 + 1] = fr[3] * v0 + fr[4] * v1 + fr[5] * v2;
    out[n * 3 + 2] = fr[6] * v0 + fr[7] * v1 + fr[8] * v2;
  }
}

// ---------------------------------------------------------------------------
extern "C" void kernel_launch(void* const* d_in, const int* in_sizes, int n_in,
                              void* d_out, int out_size, void* d_ws, size_t ws_size,
                              hipStream_t stream) {
  const float* h      = (const float*)d_in[0];
  const float* x_t    = (const float*)d_in[1];
  const float* x_cond = (const float*)d_in[2];
  const float* tau    = (const float*)d_in[3];
  const float* W_np1  = (const float*)d_in[4];
  const float* b_np1  = (const float*)d_in[5];
  const float* W_np2  = (const float*)d_in[6];
  const float* b_np2  = (const float*)d_in[7];
  const float* w_src  = (const float*)d_in[8];
  const float* b_src  = (const float*)d_in[9];
  const float* w_dst  = (const float*)d_in[10];
  const float* b_dst  = (const float*)d_in[11];
  const float* w_ns   = (const float*)d_in[12];
  const float* b_ns   = (const float*)d_in[13];
  const float* W_eg1  = (const float*)d_in[14];
  const float* b_eg1  = (const float*)d_in[15];
  const float* w_eg2  = (const float*)d_in[16];
  const float* b_eg2  = (const float*)d_in[17];
  const float* W_out1 = (const float*)d_in[18];
  const float* b_out1 = (const float*)d_in[19];
  const float* W_out2 = (const float*)d_in[20];
  const float* b_out2 = (const float*)d_in[21];
  float* out = (float*)d_out;

  const int N = in_sizes[1] / 3;  // 1024

  float* ws     = (float*)d_ws;
  float* frames = ws;                 // N*9
  float* dl     = frames + N * 9;     // N*3
  float* nh1    = dl + N * 3;         // N*256
  float* nh     = nh1 + N * 256;      // N*256
  float* srcv   = nh + N * 256;       // N
  float* dstv   = srcv + N;           // N
  float* nsv    = dstv + N;           // N
  float* msgs   = nsv + N;            // N*3

  frames_kernel<<<(N + 255) / 256, 256, 0, stream>>>(x_cond, x_t, frames, dl, N);
  node_mlp1<<<N / 4, 256, 0, stream>>>(h, dl, tau, W_np1, b_np1, nh1, N);
  node_mlp2<<<N / 4, 256, 0, stream>>>(nh1, W_np2, b_np2, w_src, b_src,
                                       w_dst, b_dst, w_ns, b_ns,
                                       nh, srcv, dstv, nsv, N);
  edge_softmax<<<N, 512, 0, stream>>>(x_t, frames, srcv, dstv, nsv,
                                      W_eg1, b_eg1, w_eg2, b_eg2, msgs, N);
  out_mlp<<<N / 4, 256, 0, stream>>>(nh, dl, msgs, frames,
                                     W_out1, b_out1, W_out2, b_out2, out, N);
}